// Round 12
// baseline (161.371 us; speedup 1.0000x reference)
//
#include <hip/hip_runtime.h>
#include <math.h>

// RC thermal model: x' = A x + b0*To(t) + Bq, RK4 h=30, T=1e6 steps.
// Per step: x_{t+1} = M x_t + c + al*To[t] + be*To[t+1].
// R20: BLK=512/CH=4 -- 2x waves/CU (16 vs 7.6) at the SAME 489-block
// geometry that measures clean (R15: WRITE 66MB FETCH 2.5MB). R19 showed
// the 64us kernel is wave-starved (cuts to setup-head/mirror/expand all
// neutral, VALU 17%); R16/17 showed 977 BLOCKS amplify traffic -- so get
// waves from block SIZE, not block count. Per-block span stays 2048 steps
// -> lookback (32 slots, M^2048jj, Pd=M^8192i) verbatim R15/R19 (PL/PD
// read from global, R19-proven). New in-block geometry: 8-wave tree
// (M^256/512/1024, 3 rounds) + Kogge-Stone wave-prefix over 8 waves
// (3 rounds, merged with tree on disjoint thread ranges) + Qw by 3
// doubling rounds. Fold/scan/prefix/expand = R16-verified CH=4 bodies.
// Two kernels (single-dispatch bought nothing, R18/19). Spin-safety:
// (512,4) => 2 blocks/CU, capacity 512 >= 489 co-resident; acquire-polls
// (R15-proven; also invalidate poisoned L2 agg lines before plain reads).

#define S_STEPS 999999
#define CH      4
#define BLK     512
#define NB      489          // 489*512*4 = 1,001,472 >= S_STEPS
#define NCHUNK  250000       // active chunks (last partial: 3 steps)
#define LASTFULL 249998      // g <= LASTFULL: To[4g+4] in bounds

// ws float offsets (16B-aligned)
#define OFF_M   0            // 144: M
#define OFF_C   144          // 12
#define OFF_AL  156          // 12
#define OFF_BE  168          // 12
#define OFF_K   192          // 72: K cols [col][12] (6 cols, CH=4)
#define OFF_P2  264          // 9*144: [l]=M^(4*2^l) l=0..5 (M^4..M^128),
                             //        [6]=M^256, [7]=M^512, [8]=M^1024
#define NLC     1560         // floats mirrored to LDS (ends at OFF_P2+9*144)
#define OFF_PL  1560         // 3*144: M^2048, M^4096, M^6144   (global reads)
#define OFF_PD  1992         // 8*144: Pd[i]=M^(8192i), i=0..7  (global reads)
#define OFF_AGG 3144         // 489*12 aggregates (end 9012)
#define OFF_FLAG 9012        // 489 int flags

#define FMA4(Q,a,b,c,d,acc) fmaf((Q).w,(d),fmaf((Q).z,(c),fmaf((Q).y,(b),fmaf((Q).x,(a),(acc)))))

// y += P(12x12 row-major, 16B-aligned) * x
__device__ __forceinline__ void mv_acc(const float* Pf, const float* x, float* y) {
  const float4* P = reinterpret_cast<const float4*>(Pf);
#pragma unroll
  for (int i = 0; i < 12; ++i) {
    float4 a = P[3*i], b = P[3*i+1], c = P[3*i+2];
    y[i] = FMA4(c, x[8],x[9],x[10],x[11],
            FMA4(b, x[4],x[5],x[6],x[7],
             FMA4(a, x[0],x[1],x[2],x[3], y[i])));
  }
}

// dot(P row (16B-aligned), xv[0..11] scalars)
__device__ __forceinline__ float rowdot(const float* Prow, const float* xv) {
  const float4* P = reinterpret_cast<const float4*>(Prow);
  float4 a = P[0], b = P[1], c = P[2];
  return FMA4(c, xv[8],xv[9],xv[10],xv[11],
          FMA4(b, xv[4],xv[5],xv[6],xv[7],
           FMA4(a, xv[0],xv[1],xv[2],xv[3], 0.f)));
}

// v = K[:,0] + sum_{s=0..4} K[:,s+1]*tos[s]  (CH=4: 6 cols)
__device__ __forceinline__ void fold_chunk(const float* cons,
                                           const float* tos, float* v) {
  const float4* Kq = reinterpret_cast<const float4*>(cons + OFF_K);
  float4 c0=Kq[0], c1=Kq[1], c2=Kq[2];
  v[0]=c0.x; v[1]=c0.y; v[2]=c0.z; v[3]=c0.w;
  v[4]=c1.x; v[5]=c1.y; v[6]=c1.z; v[7]=c1.w;
  v[8]=c2.x; v[9]=c2.y; v[10]=c2.z; v[11]=c2.w;
#pragma unroll
  for (int s = 0; s < 5; ++s) {
    float ts = tos[s];
    float4 ka=Kq[3*(s+1)], kb=Kq[3*(s+1)+1], kc=Kq[3*(s+1)+2];
    v[0]=fmaf(ka.x,ts,v[0]); v[1]=fmaf(ka.y,ts,v[1]); v[2]=fmaf(ka.z,ts,v[2]); v[3]=fmaf(ka.w,ts,v[3]);
    v[4]=fmaf(kb.x,ts,v[4]); v[5]=fmaf(kb.y,ts,v[5]); v[6]=fmaf(kb.z,ts,v[6]); v[7]=fmaf(kb.w,ts,v[7]);
    v[8]=fmaf(kc.x,ts,v[8]); v[9]=fmaf(kc.y,ts,v[9]); v[10]=fmaf(kc.z,ts,v[10]); v[11]=fmaf(kc.w,ts,v[11]);
  }
}

__global__ void __launch_bounds__(512) setup_kernel(
    const float* __restrict__ t_eval, const float* __restrict__ A,
    const float* __restrict__ Bm, const float* __restrict__ loads_raw,
    const float* __restrict__ areas, float* ws) {
  __shared__ double H1[144], H2[144], H3[144], H4[144], Md[144];
  __shared__ double Qa[144], Qb[144];
  __shared__ double C2048s[144], C4096s[144], C8192s[144];
  __shared__ double C16384s[144], C32768s[144], Pd3s[144];
  __shared__ double cd[12], ald[12], bed[12], b0d[12], bqd[12];
  __shared__ double Vv[3][12], Kd[72];
  int t = threadIdx.x;
  if (t < NB) ((int*)(ws + OFF_FLAG))[t] = 0;   // zero pred flags
  double h = (double)t_eval[1] - (double)t_eval[0];
  if (t < 144) H1[t] = h * (double)A[t];
  if (t < 12) {
    b0d[t] = (double)Bm[t*11];
    double s = 0.0;
    for (int r = 0; r < 10; ++r) {
      double gq = 50.0 / (1.0 + exp(-(double)loads_raw[10 + r]));
      s += (double)Bm[t*11 + 1 + r] * (gq * (double)areas[r]);
    }
    bqd[t] = s;
  }
  if (t < 72) Kd[t] = 0.0;
  __syncthreads();
  if (t < 144) {                              // H2 = H1*H1
    int i=t/12, j=t%12; double s=0.0;
#pragma unroll
    for (int m = 0; m < 12; ++m) s += H1[i*12+m]*H1[m*12+j];
    H2[t]=s;
  }
  __syncthreads();
  if (t < 288) {                              // H3 = H2*H1 | H4 = H2*H2
    int w=t/144, e=t%144, i=e/12, j=e%12;
    const double* Bp = w ? H2 : H1;
    double s = 0.0;
#pragma unroll
    for (int m = 0; m < 12; ++m) s += H2[i*12+m]*Bp[m*12+j];
    (w ? H4 : H3)[e] = s;
  }
  __syncthreads();
  if (t < 12) {
    double hb=0,h2b=0,h3b=0,hb0=0,h2b0=0,h3b0=0;
#pragma unroll
    for (int m = 0; m < 12; ++m) {
      hb  += H1[t*12+m]*bqd[m]; h2b  += H2[t*12+m]*bqd[m]; h3b  += H3[t*12+m]*bqd[m];
      hb0 += H1[t*12+m]*b0d[m]; h2b0 += H2[t*12+m]*b0d[m]; h3b0 += H3[t*12+m]*b0d[m];
    }
    double h6 = h / 6.0;
    cd[t]  = h6*(6.0*bqd[t] + 3.0*hb + h2b + 0.25*h3b);
    ald[t] = h6*(3.0*b0d[t] + 2.0*hb0 + 0.75*h2b0 + 0.25*h3b0);
    bed[t] = h6*(3.0*b0d[t] + hb0 + 0.25*h2b0);
    Vv[0][t]=ald[t]; Vv[1][t]=bed[t]; Vv[2][t]=cd[t];
    // r=0 K contributions (CH=4): col4 += al, col5 += be, col0 += c
    Kd[48+t] += ald[t]; Kd[60+t] += bed[t]; Kd[t] += cd[t];
  }
  if (t >= 144 && t < 288) {
    int e=t-144, i=e/12, j=e%12;
    Md[e] = (i==j ? 1.0 : 0.0) + H1[e] + 0.5*H2[e] + H3[e]/6.0 + H4[e]/24.0;
  }
  __syncthreads();
  if (t < 144) { ws[OFF_M+t] = (float)Md[t]; Qa[t] = Md[t]; }
  if (t < 12) {
    ws[OFF_C+t]=(float)cd[t]; ws[OFF_AL+t]=(float)ald[t]; ws[OFF_BE+t]=(float)bed[t];
  }
  __syncthreads();
  // chain r=1..15: src=M^(2^(r-1)) -> dst=M^(2^r). Overlapped K rounds
  // r=1..3 (threads 256..291): Vv=M^r*{al,be,c}; Kd cols (4-r),(5-r),0.
  double* src = Qa; double* dst = Qb;
  for (int r = 1; r <= 15; ++r) {
    double acc = 0.0, ks = 0.0;
    if (t < 144) {
      int i=t/12, j=t%12;
#pragma unroll
      for (int m = 0; m < 12; ++m) acc += src[i*12+m]*src[m*12+j];
    }
    int w=0, i2=0;
    if (r <= 3 && t >= 256 && t < 292) {
      w=(t-256)/12; i2=(t-256)%12;
#pragma unroll
      for (int m = 0; m < 12; ++m) ks += Md[i2*12+m]*Vv[w][m];
    }
    __syncthreads();
    if (t < 144) {
      dst[t] = acc;
      if (r >= 2 && r <= 7) ws[OFF_P2+(r-2)*144+t] = (float)acc;  // M^4..M^128
      if (r == 8)  { ws[OFF_P2+6*144+t] = (float)acc;             // M^256
                     ws[OFF_PD+t] = (t % 13 == 0) ? 1.f : 0.f; }  // Pd[0]=I
      if (r == 9)  ws[OFF_P2+7*144+t] = (float)acc;               // M^512
      if (r == 10) ws[OFF_P2+8*144+t] = (float)acc;               // M^1024
      if (r == 11) { ws[OFF_PL+t]       = (float)acc; C2048s[t]=acc; }
      if (r == 12) { ws[OFF_PL+144+t]   = (float)acc; C4096s[t]=acc; }
      if (r == 13) { ws[OFF_PD+144+t]   = (float)acc; C8192s[t]=acc; }
      if (r == 14) { ws[OFF_PD+2*144+t] = (float)acc; C16384s[t]=acc; }
      if (r == 15) { ws[OFF_PD+4*144+t] = (float)acc; C32768s[t]=acc; }
    }
    if (r <= 3 && t >= 256 && t < 292) {
      Vv[w][i2] = ks;
      if (w == 0) Kd[(4-r)*12+i2] += ks;
      else if (w == 1) Kd[(5-r)*12+i2] += ks;
      else Kd[i2] += ks;
    }
    __syncthreads();
    double* tmp = src; src = dst; dst = tmp;    // src = M^(2^r)
  }
  if (t < 72) ws[OFF_K+t] = (float)Kd[t];
  // product round A: M^6144=C2048*C4096 ; Pd3=C8192*C16384
  if (t < 288) {
    int w=t/144, e=t%144, i=e/12, j=e%12;
    const double* Ap = (w==0) ? C2048s : C8192s;
    const double* Bp = (w==0) ? C4096s : C16384s;
    double s = 0.0;
#pragma unroll
    for (int m = 0; m < 12; ++m) s += Ap[i*12+m]*Bp[m*12+j];
    if (w==0) ws[OFF_PL+2*144+e] = (float)s;
    else { ws[OFF_PD+3*144+e] = (float)s; Pd3s[e] = s; }
  }
  __syncthreads();
  // product round B: Pd5=Pd1*Pd4 ; Pd6=Pd2*Pd4 ; Pd7=Pd3*Pd4
  if (t < 432) {
    int w=t/144, e=t%144, i=e/12, j=e%12;
    const double* Ap = (w==0) ? C8192s : ((w==1) ? C16384s : Pd3s);
    double s = 0.0;
#pragma unroll
    for (int m = 0; m < 12; ++m) s += Ap[i*12+m]*C32768s[m*12+j];
    ws[OFF_PD+(5+w)*144+e] = (float)s;
  }
}

// Fused worker: 512 threads = 8 waves, 2048 steps/block. LDS-mirror
// stage-1 region; fold+scan; 8-wave tree + Kogge-Stone wave prefix
// (merged rounds); publish/spin (R15 acquire-polls); 32-slot lookback
// (PL/PD global); Qw doubling; prefix apply + 4-step expand.
__global__ void __launch_bounds__(BLK, 4) fused_scan(
    const float* __restrict__ cons, const float* __restrict__ To,
    const float* __restrict__ x0, float* __restrict__ agg,
    int* __restrict__ flags, float* __restrict__ out) {
  __shared__ __align__(16) float Lc[NLC];
  __shared__ __align__(16) float Tw[96];      // 8 wave totals
  __shared__ __align__(16) float Ta1[48];     // tree level 1 (4 nodes)
  __shared__ __align__(16) float Ta2[24];     // tree level 2 (2 nodes)
  __shared__ __align__(16) float Pa[96], Pb[96];  // wave-prefix KS buffers
  __shared__ __align__(16) float lkb[32*12];
  __shared__ __align__(16) float yv[8*12];
  __shared__ __align__(16) float zv[8*12];
  __shared__ __align__(16) float Xs[12];
  __shared__ __align__(16) float Sq[96];      // M^(256w)*Xs
  __shared__ __align__(16) float Qw[96];
  int k = threadIdx.x, b = blockIdx.x;
  int g = b*BLK + k, base = g*CH;
  bool active = (g < NCHUNK), fullc = (g <= LASTFULL);
  float to_[5];
#pragma unroll
  for (int i = 0; i < 5; ++i) to_[i] = 0.f;
  if (active) {
    const float4* tp = reinterpret_cast<const float4*>(To + base);
    float4 ta = tp[0];
    to_[0]=ta.x; to_[1]=ta.y; to_[2]=ta.z; to_[3]=ta.w;
    to_[4] = fullc ? To[base+4] : 0.f;
  }
  {                                  // mirror stage-1: cons[0..1560)
    const float4* s4 = reinterpret_cast<const float4*>(cons);
    float4* d4 = reinterpret_cast<float4*>(Lc);
    if (k < NLC/4) d4[k] = s4[k];
  }
  __syncthreads();
  const float* lc = Lc;
  float v[12];
  if (fullc) fold_chunk(lc, to_, v);
  else {
#pragma unroll
    for (int i = 0; i < 12; ++i) v[i] = 0.f;
  }
  if (g == 0) {                      // fold x0 into chunk 0: v += M^4 x0
    float xi[12];
#pragma unroll
    for (int i = 0; i < 12; ++i) xi[i] = x0[i];
    mv_acc(lc + OFF_P2, xi, v);
  }
  int j = k & 63, w = k >> 6;        // 8 waves
#pragma unroll
  for (int l = 0; l < 6; ++l) {      // in-wave inclusive scan, M^(4*2^l)
    int off = 1 << l;
    float nb[12];
#pragma unroll
    for (int i = 0; i < 12; ++i) nb[i] = __shfl_up(v[i], (unsigned)off, 64);
    if (j >= off) mv_acc(lc + OFF_P2 + l*144, nb, v);
  }
  float se[12];                      // exclusive in-wave scan
#pragma unroll
  for (int i = 0; i < 12; ++i) {
    float u = __shfl_up(v[i], 1u, 64);
    se[i] = (j == 0) ? 0.f : u;
  }
  if (j == 63) {
#pragma unroll
    for (int i = 0; i < 12; ++i) Tw[w*12 + i] = v[i];
  }
  __syncthreads();
  // Round A: tree L1 (k<48) | wave-prefix KS level0, M^256 (k in [96,192))
  if (k < 48) {
    int q = k/12, comp = k - q*12;
    Ta1[k] = rowdot(lc + OFF_P2 + 6*144 + comp*12, Tw + 2*q*12)
           + Tw[(2*q+1)*12 + comp];
  } else if (k >= 96 && k < 192) {
    int idx = k - 96, wv = idx/12, comp = idx - wv*12;
    Pa[idx] = (wv == 0) ? Tw[idx]
            : rowdot(lc + OFF_P2 + 6*144 + comp*12, Tw + (wv-1)*12) + Tw[idx];
  }
  __syncthreads();
  // Round B: tree L2 (k<24) | KS level1, M^512
  if (k < 24) {
    int p = k/12, comp = k - p*12;
    Ta2[k] = rowdot(lc + OFF_P2 + 7*144 + comp*12, Ta1 + 2*p*12)
           + Ta1[(2*p+1)*12 + comp];
  } else if (k >= 96 && k < 192) {
    int idx = k - 96, wv = idx/12, comp = idx - wv*12;
    Pb[idx] = (wv < 2) ? Pa[idx]
            : rowdot(lc + OFF_P2 + 7*144 + comp*12, Pa + (wv-2)*12) + Pa[idx];
  }
  __syncthreads();
  // Round C: agg (k<12, LLC store) | KS level2, M^1024 -> Pa = inclusive
  if (k < 12) {
    float val = rowdot(lc + OFF_P2 + 8*144 + k*12, Ta2) + Ta2[12 + k];
    __hip_atomic_store(&agg[b*12 + k], val, __ATOMIC_RELAXED,
                       __HIP_MEMORY_SCOPE_AGENT);
  } else if (k >= 96 && k < 192) {
    int idx = k - 96, wv = idx/12, comp = idx - wv*12;
    Pa[idx] = (wv < 4) ? Pb[idx]
            : rowdot(lc + OFF_P2 + 8*144 + comp*12, Pb + (wv-4)*12) + Pb[idx];
  }
  __syncthreads();                   // barrier drains vmcnt (agg at LLC)
  if (k == 0)                        // publish: release flag
    __hip_atomic_store(&flags[b], 1, __ATOMIC_RELEASE,
                       __HIP_MEMORY_SCOPE_AGENT);
  // spin on 32 predecessors (acquire polls -- also invalidate stale L2)
  if (k < 32) {
    int src = b - 1 - k;
    if (src >= 0) {
      while (__hip_atomic_load(&flags[src], __ATOMIC_ACQUIRE,
                               __HIP_MEMORY_SCOPE_AGENT) == 0) {
        __builtin_amdgcn_s_sleep(1);
      }
    }
  }
  __syncthreads();
  // lookback stage 1: slot=4i+jj: lkb[slot] = M^(2048*jj)*agg[b-1-slot];
  // PL from GLOBAL ws (L2-resident)
  if (k < 384) {
    int slot = k / 12, comp = k - slot*12;
    int src = b - 1 - slot;
    float acc = 0.f;
    if (src >= 0) {
      int jj = slot & 3;
      const float* ag = agg + src*12;
      acc = (jj == 0) ? ag[comp]
          : rowdot(cons + OFF_PL + (jj-1)*144 + comp*12, ag);
    }
    lkb[k] = acc;
  }
  __syncthreads();
  if (k < 96) {                      // yv[i] = sum_jj lkb[4i+jj]
    int i = k/12, comp = k - i*12;
    yv[k] = lkb[(4*i)*12+comp] + lkb[(4*i+1)*12+comp]
          + lkb[(4*i+2)*12+comp] + lkb[(4*i+3)*12+comp];
  }
  __syncthreads();
  if (k < 96) {                      // zv[i] = M^(8192i)*yv[i] (PD global)
    int i = k/12, comp = k - i*12;
    zv[k] = (i == 0) ? yv[comp]
          : rowdot(cons + OFF_PD + i*144 + comp*12, yv + i*12);
  }
  __syncthreads();
  if (k < 12) {                      // Xs = sum_i zv[i]
    float s = 0.f;
#pragma unroll
    for (int i = 0; i < 8; ++i) s += zv[i*12 + k];
    Xs[k] = s;
  }
  __syncthreads();
  // Sq doubling round 1: Sq[0]=Xs, Sq[1]=M^256*Xs
  if (k < 12) {
    Sq[k] = Xs[k];
    Sq[12 + k] = rowdot(lc + OFF_P2 + 6*144 + k*12, Xs);
  }
  __syncthreads();
  // round 2: Sq[2,3] = M^512 * Sq[0,1]
  if (k < 24) {
    int q = k/12, comp = k - q*12;
    Sq[(2+q)*12 + comp] = rowdot(lc + OFF_P2 + 7*144 + comp*12, Sq + q*12);
  }
  __syncthreads();
  // round 3: Sq[4..7] = M^1024 * Sq[0..3]
  if (k < 48) {
    int q = k/12, comp = k - q*12;
    Sq[(4+q)*12 + comp] = rowdot(lc + OFF_P2 + 8*144 + comp*12, Sq + q*12);
  }
  __syncthreads();
  // Qw[w] = Sq[w] + Pw_exclusive[w]  (exclusive = Pa[w-1], 0 for w=0)
  if (k < 96) {
    int wv = k/12;
    Qw[k] = Sq[k] + ((wv == 0) ? 0.f : Pa[k - 12]);
  }
  __syncthreads();
  if (!active) return;               // all barriers done
  // per-thread: x = M^(4j)*Qw[w] + se   (bits of j, P2[0..5])
  float x[12];
#pragma unroll
  for (int i = 0; i < 12; ++i) x[i] = Qw[w*12 + i];
#pragma unroll
  for (int l = 0; l < 6; ++l) {
    if ((j >> l) & 1) {
      float vn[12];
#pragma unroll
      for (int i = 0; i < 12; ++i) vn[i] = 0.f;
      mv_acc(lc + OFF_P2 + l*144, x, vn);
#pragma unroll
      for (int i = 0; i < 12; ++i) x[i] = vn[i];
    }
  }
#pragma unroll
  for (int i = 0; i < 12; ++i) x[i] += se[i];
  if (b == 0 && k == 0) {
#pragma unroll
    for (int i = 0; i < 12; ++i) x[i] += x0[i];      // start state = x0
#pragma unroll
    for (int i = 0; i < 12; ++i) out[i] = x0[i];     // row 0
  }
  // expand: 4 unconditional steps, predicated stores (NO break)
  float cv[12], av[12], bv[12];
#pragma unroll
  for (int i = 0; i < 12; ++i) {
    cv[i] = lc[OFF_C + i]; av[i] = lc[OFF_AL + i]; bv[i] = lc[OFF_BE + i];
  }
  const float4* Mq = reinterpret_cast<const float4*>(lc + OFF_M);
#pragma unroll
  for (int s = 0; s < CH; ++s) {
    float tot = to_[s], ton = (s < CH-1) ? to_[s+1] : to_[4];
    float xn[12];
#pragma unroll
    for (int i = 0; i < 12; ++i) {
      float4 a = Mq[3*i], bq = Mq[3*i+1], c = Mq[3*i+2];
      xn[i] = FMA4(c, x[8],x[9],x[10],x[11],
               FMA4(bq, x[4],x[5],x[6],x[7],
                FMA4(a, x[0],x[1],x[2],x[3],
                 fmaf(bv[i],ton,fmaf(av[i],tot,cv[i])))));
    }
    int tt = base + s;
    if (tt < S_STEPS) {
      float4* op = reinterpret_cast<float4*>(out + (size_t)(tt+1)*12);
      op[0] = make_float4(xn[0],xn[1],xn[2],xn[3]);
      op[1] = make_float4(xn[4],xn[5],xn[6],xn[7]);
      op[2] = make_float4(xn[8],xn[9],xn[10],xn[11]);
    }
#pragma unroll
    for (int i = 0; i < 12; ++i) x[i] = xn[i];
  }
}

extern "C" void kernel_launch(void* const* d_in, const int* in_sizes, int n_in,
                              void* d_out, int out_size, void* d_ws, size_t ws_size,
                              hipStream_t stream) {
  const float* t_eval    = (const float*)d_in[0];
  const float* x0        = (const float*)d_in[1];
  const float* A         = (const float*)d_in[2];
  const float* B         = (const float*)d_in[3];
  const float* To        = (const float*)d_in[4];
  const float* loads_raw = (const float*)d_in[5];
  const float* areas     = (const float*)d_in[6];
  float* out = (float*)d_out;
  float* ws  = (float*)d_ws;

  setup_kernel<<<1, 512, 0, stream>>>(t_eval, A, B, loads_raw, areas, ws);
  fused_scan<<<NB, BLK, 0, stream>>>(ws, To, x0, ws + OFF_AGG,
                                     (int*)(ws + OFF_FLAG), out);
}

// Round 13
// 136.649 us; speedup vs baseline: 1.1809x; 1.1809x over previous
//
#include <hip/hip_runtime.h>
#include <math.h>

// RC thermal model: x' = A x + b0*To(t) + Bq, RK4 h=30, T=1e6 steps.
// Per step: x_{t+1} = M x_t + c + al*To[t] + be*To[t+1].
// R21: R15 base (CH=8, 489x256, publish/spin, LDS-mirrored cons -- best
// verified 130.9us) + CONTIGUOUS STORE FLUSH. Diagnosis: R15 writes
// 66.8MB/51.3us = 1.3TB/s effective (5x under streaming), WRITE already
// 1.4x the 48MB output; CH=4 variants (R16/17/20) explode to 2.8x
// regardless of blocks/atomics => scattered 16B stores at 384B lane
// stride leave 128B lines partial across the 8-step loop -> evict ->
// HBM RMW. Fix: compute 8 rows into 24 registered float4s (static
// indexing only); per wave flush the 24KB region in 4 sub-passes via
// 6KB LDS stage: 16 src lanes ds_write -> wave-local lgkmcnt(0) -> all
// 64 lanes store 1KB CONTIGUOUS per instruction (8 lanes share each
// 128B line in the same instruction -> no partials). XOR swizzle
// idx^((idx>>3)&7) = bank-spread writes + conflict-free reads,
// bijective. Tail waves (!__all(fullc)) use R15's predicated stores.
// All math through x is byte-identical R15. LDS ~40KB -> 2 blocks/CU.

#define S_STEPS 999999
#define CH      8
#define BLK     256
#define NB      489          // 489*256*8 = 1,001,472 >= S_STEPS
#define NCHUNK  125000       // active chunks (last partial: 7 steps)
#define LASTFULL 124998      // g <= LASTFULL: To[8g+8] in bounds

// ws float offsets (16B-aligned)
#define OFF_M   0            // 144: M
#define OFF_C   144          // 12
#define OFF_AL  156          // 12
#define OFF_BE  168          // 12
#define OFF_K   192          // 120: K cols [col][12] (10 cols)
#define OFF_P2  320          // 8*144: [l]=M^(8*2^l) l=0..5, [6]=M^512, [7]=M^1024
#define OFF_PA  1472         // 144: M^1536
#define OFF_PL  1616         // 3*144: M^2048, M^4096, M^6144
#define OFF_PD  2048         // 8*144: Pd[i]=M^(8192*i), i=0..7
#define NCONS   3200         // floats mirrored to LDS
#define OFF_AGG 3200         // 489*12 aggregates (end 9068)
#define OFF_FLAG 9072        // 489 int flags

#define FMA4(Q,a,b,c,d,acc) fmaf((Q).w,(d),fmaf((Q).z,(c),fmaf((Q).y,(b),fmaf((Q).x,(a),(acc)))))

// y += P(12x12 row-major, 16B-aligned) * x
__device__ __forceinline__ void mv_acc(const float* Pf, const float* x, float* y) {
  const float4* P = reinterpret_cast<const float4*>(Pf);
#pragma unroll
  for (int i = 0; i < 12; ++i) {
    float4 a = P[3*i], b = P[3*i+1], c = P[3*i+2];
    y[i] = FMA4(c, x[8],x[9],x[10],x[11],
            FMA4(b, x[4],x[5],x[6],x[7],
             FMA4(a, x[0],x[1],x[2],x[3], y[i])));
  }
}

// dot(P row (16B-aligned), xv[0..11] scalars)
__device__ __forceinline__ float rowdot(const float* Prow, const float* xv) {
  const float4* P = reinterpret_cast<const float4*>(Prow);
  float4 a = P[0], b = P[1], c = P[2];
  return FMA4(c, xv[8],xv[9],xv[10],xv[11],
          FMA4(b, xv[4],xv[5],xv[6],xv[7],
           FMA4(a, xv[0],xv[1],xv[2],xv[3], 0.f)));
}

// v = K[:,0] + sum_{s=0..8} K[:,s+1]*tos[s]
__device__ __forceinline__ void fold_chunk(const float* cons,
                                           const float* tos, float* v) {
  const float4* Kq = reinterpret_cast<const float4*>(cons + OFF_K);
  float4 c0=Kq[0], c1=Kq[1], c2=Kq[2];
  v[0]=c0.x; v[1]=c0.y; v[2]=c0.z; v[3]=c0.w;
  v[4]=c1.x; v[5]=c1.y; v[6]=c1.z; v[7]=c1.w;
  v[8]=c2.x; v[9]=c2.y; v[10]=c2.z; v[11]=c2.w;
#pragma unroll
  for (int s = 0; s < 9; ++s) {
    float ts = tos[s];
    float4 ka=Kq[3*(s+1)], kb=Kq[3*(s+1)+1], kc=Kq[3*(s+1)+2];
    v[0]=fmaf(ka.x,ts,v[0]); v[1]=fmaf(ka.y,ts,v[1]); v[2]=fmaf(ka.z,ts,v[2]); v[3]=fmaf(ka.w,ts,v[3]);
    v[4]=fmaf(kb.x,ts,v[4]); v[5]=fmaf(kb.y,ts,v[5]); v[6]=fmaf(kb.z,ts,v[6]); v[7]=fmaf(kb.w,ts,v[7]);
    v[8]=fmaf(kc.x,ts,v[8]); v[9]=fmaf(kc.y,ts,v[9]); v[10]=fmaf(kc.z,ts,v[10]); v[11]=fmaf(kc.w,ts,v[11]);
  }
}

__global__ void __launch_bounds__(512) setup_kernel(
    const float* __restrict__ t_eval, const float* __restrict__ A,
    const float* __restrict__ Bm, const float* __restrict__ loads_raw,
    const float* __restrict__ areas, float* ws) {
  __shared__ double H1[144], H2[144], H3[144], H4[144], Md[144];
  __shared__ double Qa[144], Qb[144];
  __shared__ double C512s[144], C1024s[144], C2048s[144], C4096s[144];
  __shared__ double C8192s[144], C16384s[144], C32768s[144], Pd3s[144];
  __shared__ double cd[12], ald[12], bed[12], b0d[12], bqd[12];
  __shared__ double Vv[3][12], Kd[120];
  int t = threadIdx.x;
  if (t < NB) ((int*)(ws + OFF_FLAG))[t] = 0;   // reset lookback flags
  double h = (double)t_eval[1] - (double)t_eval[0];
  if (t < 144) H1[t] = h * (double)A[t];
  if (t < 12) {
    b0d[t] = (double)Bm[t*11];
    double s = 0.0;
    for (int r = 0; r < 10; ++r) {
      double gq = 50.0 / (1.0 + exp(-(double)loads_raw[10 + r]));
      s += (double)Bm[t*11 + 1 + r] * (gq * (double)areas[r]);
    }
    bqd[t] = s;
  }
  if (t < 120) Kd[t] = 0.0;
  __syncthreads();
  if (t < 144) {                              // H2 = H1*H1
    int i=t/12, j=t%12; double s=0.0;
#pragma unroll
    for (int m = 0; m < 12; ++m) s += H1[i*12+m]*H1[m*12+j];
    H2[t]=s;
  }
  __syncthreads();
  if (t < 288) {                              // H3 = H2*H1 | H4 = H2*H2
    int w=t/144, e=t%144, i=e/12, j=e%12;
    const double* Bp = w ? H2 : H1;
    double s = 0.0;
#pragma unroll
    for (int m = 0; m < 12; ++m) s += H2[i*12+m]*Bp[m*12+j];
    (w ? H4 : H3)[e] = s;
  }
  __syncthreads();
  if (t < 12) {
    double hb=0,h2b=0,h3b=0,hb0=0,h2b0=0,h3b0=0;
#pragma unroll
    for (int m = 0; m < 12; ++m) {
      hb  += H1[t*12+m]*bqd[m]; h2b  += H2[t*12+m]*bqd[m]; h3b  += H3[t*12+m]*bqd[m];
      hb0 += H1[t*12+m]*b0d[m]; h2b0 += H2[t*12+m]*b0d[m]; h3b0 += H3[t*12+m]*b0d[m];
    }
    double h6 = h / 6.0;
    cd[t]  = h6*(6.0*bqd[t] + 3.0*hb + h2b + 0.25*h3b);
    ald[t] = h6*(3.0*b0d[t] + 2.0*hb0 + 0.75*h2b0 + 0.25*h3b0);
    bed[t] = h6*(3.0*b0d[t] + hb0 + 0.25*h2b0);
    Vv[0][t]=ald[t]; Vv[1][t]=bed[t]; Vv[2][t]=cd[t];
    // r=0 K contributions (CH=8): col8 += al, col9 += be, col0 += c
    Kd[96+t] += ald[t]; Kd[108+t] += bed[t]; Kd[t] += cd[t];
  }
  if (t >= 144 && t < 288) {
    int e=t-144, i=e/12, j=e%12;
    Md[e] = (i==j ? 1.0 : 0.0) + H1[e] + 0.5*H2[e] + H3[e]/6.0 + H4[e]/24.0;
  }
  __syncthreads();
  if (t < 144) { ws[OFF_M+t] = (float)Md[t]; Qa[t] = Md[t]; }
  if (t < 12) {
    ws[OFF_C+t]=(float)cd[t]; ws[OFF_AL+t]=(float)ald[t]; ws[OFF_BE+t]=(float)bed[t];
  }
  __syncthreads();
  // chain r=1..15: src=M^(2^(r-1)) -> dst=M^(2^r). Overlapped K rounds
  // r=1..7 (threads 256..291): Vv=M^r*{al,be,c}; Kd cols (8-r),(9-r),0.
  double* src = Qa; double* dst = Qb;
  for (int r = 1; r <= 15; ++r) {
    double acc = 0.0, ks = 0.0;
    if (t < 144) {
      int i=t/12, j=t%12;
#pragma unroll
      for (int m = 0; m < 12; ++m) acc += src[i*12+m]*src[m*12+j];
    }
    int w=0, i2=0;
    if (r <= 7 && t >= 256 && t < 292) {
      w=(t-256)/12; i2=(t-256)%12;
#pragma unroll
      for (int m = 0; m < 12; ++m) ks += Md[i2*12+m]*Vv[w][m];
    }
    __syncthreads();
    if (t < 144) {
      dst[t] = acc;
      if (r >= 3 && r <= 8) ws[OFF_P2+(r-3)*144+t] = (float)acc;  // M^8..M^256
      if (r == 9)  { ws[OFF_P2+6*144+t] = (float)acc; C512s[t]=acc; }
      if (r == 10) { ws[OFF_P2+7*144+t] = (float)acc; C1024s[t]=acc; }
      if (r == 11) { ws[OFF_PL+t]       = (float)acc; C2048s[t]=acc; }
      if (r == 12) { ws[OFF_PL+144+t]   = (float)acc; C4096s[t]=acc; }
      if (r == 13) { ws[OFF_PD+144+t]   = (float)acc; C8192s[t]=acc; }
      if (r == 14) { ws[OFF_PD+2*144+t] = (float)acc; C16384s[t]=acc; }
      if (r == 15) { ws[OFF_PD+4*144+t] = (float)acc; C32768s[t]=acc; }
      if (r == 8)  ws[OFF_PD+t] = (t % 13 == 0) ? 1.f : 0.f;      // Pd[0]=I
    }
    if (r <= 7 && t >= 256 && t < 292) {
      Vv[w][i2] = ks;
      if (w == 0) Kd[(8-r)*12+i2] += ks;
      else if (w == 1) Kd[(9-r)*12+i2] += ks;
      else Kd[i2] += ks;
    }
    __syncthreads();
    double* tmp = src; src = dst; dst = tmp;    // src = M^(2^r)
  }
  if (t < 120) ws[OFF_K+t] = (float)Kd[t];
  // product round A: M^1536=C512*C1024 ; M^6144=C2048*C4096 ;
  //                  Pd3=C8192*C16384
  if (t < 432) {
    int w=t/144, e=t%144, i=e/12, j=e%12;
    const double* Ap = (w==0) ? C512s  : ((w==1) ? C2048s : C8192s);
    const double* Bp = (w==0) ? C1024s : ((w==1) ? C4096s : C16384s);
    double s = 0.0;
#pragma unroll
    for (int m = 0; m < 12; ++m) s += Ap[i*12+m]*Bp[m*12+j];
    if (w==0) ws[OFF_PA+e] = (float)s;
    else if (w==1) ws[OFF_PL+2*144+e] = (float)s;
    else { ws[OFF_PD+3*144+e] = (float)s; Pd3s[e] = s; }
  }
  __syncthreads();
  // product round B: Pd5=Pd1*Pd4 ; Pd6=Pd2*Pd4 ; Pd7=Pd3*Pd4
  if (t < 432) {
    int w=t/144, e=t%144, i=e/12, j=e%12;
    const double* Ap = (w==0) ? C8192s : ((w==1) ? C16384s : Pd3s);
    double s = 0.0;
#pragma unroll
    for (int m = 0; m < 12; ++m) s += Ap[i*12+m]*C32768s[m*12+j];
    ws[OFF_PD+(5+w)*144+e] = (float)s;
  }
}

// Fused: LDS-mirror cons; fold+scan ONCE; publish agg[b] (release flag);
// spin on 32 predecessor flags (acquire); truncated lookback + merged
// prefix + 8-step expand with CONTIGUOUS LDS-bounced store flush.
__global__ void __launch_bounds__(BLK, 2) fused_scan(
    const float* __restrict__ cons, const float* __restrict__ To,
    const float* __restrict__ x0, float* __restrict__ agg,
    int* __restrict__ flags, float* __restrict__ out) {
  __shared__ __align__(16) float Lc[NCONS];   // LDS mirror of cons
  __shared__ __align__(16) float4 Stg[4*384]; // 4 waves x 6KB store stage
  __shared__ __align__(16) float Tw[48];      // wave totals
  __shared__ __align__(16) float Ta[24];      // agg tree level 1
  __shared__ __align__(16) float Pw[48];      // wave exclusive prefixes
  __shared__ __align__(16) float lkb[32*12];  // lookback stage-1 partials
  __shared__ __align__(16) float yv[8*12];
  __shared__ __align__(16) float zv[8*12];
  __shared__ __align__(16) float Xs[12];
  __shared__ __align__(16) float Qw[48];      // M^(512w)*Xs + Pw
  int k = threadIdx.x, b = blockIdx.x;
  int g = b*BLK + k, base = g*CH;
  bool active = (g < NCHUNK), fullc = (g <= LASTFULL);
  float to_[9];
#pragma unroll
  for (int i = 0; i < 9; ++i) to_[i] = 0.f;
  if (active) {
    const float4* tp = reinterpret_cast<const float4*>(To + base);
    float4 ta = tp[0], tb = tp[1];
    to_[0]=ta.x; to_[1]=ta.y; to_[2]=ta.z; to_[3]=ta.w;
    to_[4]=tb.x; to_[5]=tb.y; to_[6]=tb.z; to_[7]=tb.w;
    to_[8] = fullc ? To[base+8] : 0.f;
  }
  {                                  // mirror cons -> LDS (800 float4)
    const float4* s4 = reinterpret_cast<const float4*>(cons);
    float4* d4 = reinterpret_cast<float4*>(Lc);
#pragma unroll
    for (int r = 0; r < 4; ++r) {
      int idx = k + r*BLK;
      if (idx < NCONS/4) d4[idx] = s4[idx];
    }
  }
  __syncthreads();
  const float* lc = Lc;              // all constant reads now LDS
  float v[12];
  if (fullc) fold_chunk(lc, to_, v);
  else {
#pragma unroll
    for (int i = 0; i < 12; ++i) v[i] = 0.f;
  }
  if (g == 0) {                      // fold x0 into chunk 0: v += M^8 x0
    float xi[12];
#pragma unroll
    for (int i = 0; i < 12; ++i) xi[i] = x0[i];
    mv_acc(lc + OFF_P2, xi, v);
  }
  int j = k & 63, w = k >> 6;
#pragma unroll
  for (int l = 0; l < 6; ++l) {      // in-wave inclusive scan
    int off = 1 << l;
    float nb[12];
#pragma unroll
    for (int i = 0; i < 12; ++i) nb[i] = __shfl_up(v[i], (unsigned)off, 64);
    if (j >= off) mv_acc(lc + OFF_P2 + l*144, nb, v);
  }
  float se[12];                      // exclusive in-wave scan
#pragma unroll
  for (int i = 0; i < 12; ++i) {
    float u = __shfl_up(v[i], 1u, 64);
    se[i] = (j == 0) ? 0.f : u;
  }
  if (j == 63) {
#pragma unroll
    for (int i = 0; i < 12; ++i) Tw[w*12 + i] = v[i];
  }
  __syncthreads();
  if (k < 24) {                      // (T0,T1),(T2,T3): M^512*left + right
    int p = k/12, comp = k - p*12;
    Ta[k] = rowdot(lc + OFF_P2 + 6*144 + comp*12, Tw + 2*p*12)
          + Tw[(2*p+1)*12 + comp];
  }
  __syncthreads();
  if (k < 12) {                      // agg[b] = M^1024*Ta0 + Ta1 (agent)
    float val = rowdot(lc + OFF_P2 + 7*144 + k*12, Ta) + Ta[12 + k];
    __hip_atomic_store(&agg[b*12 + k], val, __ATOMIC_RELAXED,
                       __HIP_MEMORY_SCOPE_AGENT);
  }
  __syncthreads();
  if (k == 0)                        // publish: release flag
    __hip_atomic_store(&flags[b], 1, __ATOMIC_RELEASE,
                       __HIP_MEMORY_SCOPE_AGENT);
  // spin on 32 predecessors (threads k<32, one flag each)
  if (k < 32) {
    int src = b - 1 - k;
    if (src >= 0) {
      while (__hip_atomic_load(&flags[src], __ATOMIC_ACQUIRE,
                               __HIP_MEMORY_SCOPE_AGENT) == 0) {
        __builtin_amdgcn_s_sleep(1);
      }
    }
  }
  __syncthreads();
  // lookback stage 1: slot=4i+jj: lkb[slot] = M^(2048*jj)*agg[b-1-slot]
#pragma unroll
  for (int r = 0; r < 2; ++r) {
    int idx = k + r*BLK;             // covers 384 = 32*12
    if (idx < 384) {
      int slot = idx / 12, comp = idx - slot*12;
      int src = b - 1 - slot;
      float acc = 0.f;
      if (src >= 0) {
        int jj = slot & 3;
        const float* ag = agg + src*12;
        acc = (jj == 0) ? ag[comp]
            : rowdot(lc + OFF_PL + (jj-1)*144 + comp*12, ag);
      }
      lkb[idx] = acc;
    }
  }
  __syncthreads();
  // yv[i] = sum_jj lkb[4i+jj]  (k<96)  |  Pw: P0=0, P1=T0  (k in [192,216))
  if (k < 96) {
    int i = k/12, comp = k - i*12;
    yv[k] = lkb[(4*i)*12+comp] + lkb[(4*i+1)*12+comp]
          + lkb[(4*i+2)*12+comp] + lkb[(4*i+3)*12+comp];
  } else if (k >= 192 && k < 216) {
    int q = k - 192;                 // 0..23
    if (q < 12) Pw[q] = 0.f;         // P0
    else Pw[q] = Tw[q-12];           // P1 = T0
  }
  __syncthreads();
  // zv[i] = M^(8192i)*yv[i] (k<96) | P2 = M^512*P1 + T1 (k in [192,204))
  if (k < 96) {
    int i = k/12, comp = k - i*12;
    zv[k] = (i == 0) ? yv[comp]
          : rowdot(lc + OFF_PD + i*144 + comp*12, yv + i*12);
  } else if (k >= 192 && k < 204) {
    int comp = k - 192;
    Pw[24+comp] = rowdot(lc + OFF_P2 + 6*144 + comp*12, Pw+12) + Tw[12+comp];
  }
  __syncthreads();
  // Xs = sum_i zv[i] (k<12) | P3 = M^512*P2 + T2 (k in [192,204))
  if (k < 12) {
    float s = 0.f;
#pragma unroll
    for (int i = 0; i < 8; ++i) s += zv[i*12 + k];
    Xs[k] = s;
  } else if (k >= 192 && k < 204) {
    int comp = k - 192;
    Pw[36+comp] = rowdot(lc + OFF_P2 + 6*144 + comp*12, Pw+24) + Tw[24+comp];
  }
  __syncthreads();
  // Qw[w] = M^(512w)*Xs + Pw[w]  (w=0..3; matrices I, M^512, M^1024, M^1536)
  if (k < 48) {
    int ww = k/12, comp = k - ww*12;
    float acc;
    if (ww == 0) acc = Xs[comp];
    else if (ww == 1) acc = rowdot(lc + OFF_P2 + 6*144 + comp*12, Xs);
    else if (ww == 2) acc = rowdot(lc + OFF_P2 + 7*144 + comp*12, Xs);
    else acc = rowdot(lc + OFF_PA + comp*12, Xs);
    Qw[k] = acc + Pw[k];
  }
  __syncthreads();
  if (!active) return;               // all barriers done
  // per-thread: x = M^(8j)*Qw[w] + se   (bits of j, P2[0..5])
  float x[12];
#pragma unroll
  for (int i = 0; i < 12; ++i) x[i] = Qw[w*12 + i];
#pragma unroll
  for (int l = 0; l < 6; ++l) {
    if ((j >> l) & 1) {
      float vn[12];
#pragma unroll
      for (int i = 0; i < 12; ++i) vn[i] = 0.f;
      mv_acc(lc + OFF_P2 + l*144, x, vn);
#pragma unroll
      for (int i = 0; i < 12; ++i) x[i] = vn[i];
    }
  }
#pragma unroll
  for (int i = 0; i < 12; ++i) x[i] += se[i];
  if (b == 0 && k == 0) {
#pragma unroll
    for (int i = 0; i < 12; ++i) x[i] += x0[i];      // start state = x0
#pragma unroll
    for (int i = 0; i < 12; ++i) out[i] = x0[i];     // row 0
  }
  // expand: 8 steps into 24 registered float4s (static indexing only)
  float cv[12], av[12], bv[12];
#pragma unroll
  for (int i = 0; i < 12; ++i) {
    cv[i] = lc[OFF_C + i]; av[i] = lc[OFF_AL + i]; bv[i] = lc[OFF_BE + i];
  }
  const float4* Mq = reinterpret_cast<const float4*>(lc + OFF_M);
  float4 xr[24];
#pragma unroll
  for (int s = 0; s < CH; ++s) {
    float tot = to_[s], ton = to_[s+1];
    float xn[12];
#pragma unroll
    for (int i = 0; i < 12; ++i) {
      float4 a = Mq[3*i], bq = Mq[3*i+1], c = Mq[3*i+2];
      xn[i] = FMA4(c, x[8],x[9],x[10],x[11],
               FMA4(bq, x[4],x[5],x[6],x[7],
                FMA4(a, x[0],x[1],x[2],x[3],
                 fmaf(bv[i],ton,fmaf(av[i],tot,cv[i])))));
    }
    xr[3*s]   = make_float4(xn[0],xn[1],xn[2],xn[3]);
    xr[3*s+1] = make_float4(xn[4],xn[5],xn[6],xn[7]);
    xr[3*s+2] = make_float4(xn[8],xn[9],xn[10],xn[11]);
#pragma unroll
    for (int i = 0; i < 12; ++i) x[i] = xn[i];
  }
  // store flush
  bool fastwave = __all(fullc);
  if (fastwave) {
    // wave region = rows [8*gw0+1, 8*gw0+512] = 1536 f4, contiguous.
    int gw0 = g - j;
    float4* Sw = Stg + w*384;
    float4* gout = reinterpret_cast<float4*>(out) + (size_t)(8*(size_t)gw0 + 1)*3;
#pragma unroll
    for (int h = 0; h < 4; ++h) {
      if ((j >> 4) == h) {           // 16 source lanes stage 24 f4 each
        int sb = (j & 15) * 24;
#pragma unroll
        for (int c = 0; c < 24; ++c) {
          int wi = sb + c;
          Sw[wi ^ ((wi >> 3) & 7)] = xr[c];   // bank-spread swizzle
        }
      }
      asm volatile("s_waitcnt lgkmcnt(0)" ::: "memory");
#pragma unroll
      for (int q = 0; q < 6; ++q) {  // 1KB contiguous per instruction
        int ri = q*64 + j;
        gout[h*384 + ri] = Sw[ri ^ ((ri >> 3) & 7)];
      }
    }
  } else {                           // tail wave: predicated direct stores
#pragma unroll
    for (int s = 0; s < CH; ++s) {
      int tt = base + s;
      if (tt < S_STEPS) {
        float4* op = reinterpret_cast<float4*>(out + (size_t)(tt+1)*12);
        op[0] = xr[3*s]; op[1] = xr[3*s+1]; op[2] = xr[3*s+2];
      }
    }
  }
}

extern "C" void kernel_launch(void* const* d_in, const int* in_sizes, int n_in,
                              void* d_out, int out_size, void* d_ws, size_t ws_size,
                              hipStream_t stream) {
  const float* t_eval    = (const float*)d_in[0];
  const float* x0        = (const float*)d_in[1];
  const float* A         = (const float*)d_in[2];
  const float* B         = (const float*)d_in[3];
  const float* To        = (const float*)d_in[4];
  const float* loads_raw = (const float*)d_in[5];
  const float* areas     = (const float*)d_in[6];
  float* out = (float*)d_out;
  float* ws  = (float*)d_ws;

  setup_kernel<<<1, 512, 0, stream>>>(t_eval, A, B, loads_raw, areas, ws);
  fused_scan<<<NB, BLK, 0, stream>>>(ws, To, x0, ws + OFF_AGG,
                                     (int*)(ws + OFF_FLAG), out);
}

// Round 14
// 130.457 us; speedup vs baseline: 1.2370x; 1.0475x over previous
//
#include <hip/hip_runtime.h>
#include <math.h>

// RC thermal model: x' = A x + b0*To(t) + Bq, RK4 h=30, T=1e6 steps.
// Per step: x_{t+1} = M x_t + c + al*To[t] + be*To[t+1].
// R22: REVERT to R15 (best verified, 130.9us) as the terminal kernel.
// Session record: six orthogonal structural attacks on the 51us fused
// kernel all failed or were neutral -- R9 work-halving (neutral: latency-
// bound), R11 grid.sync fusion (-50us regression), R12 register preload
// (scratch demotion), R14 LDS-mirrored constants (-4us, kept here),
// R16/17/20 occupancy doubling (CH=4 traffic explosion: WRITE 2.6x /
// FETCH 15x regardless of blocks/atomics/flavor), R18/19 setup overlap +
// expand hoist (neutral), R21 contiguous store flush (neutral-negative).
// All pipes <30% busy throughout; per-iteration total is pinned at
// ~131us = harness ws-fill ~44us (268MB @76% HBM peak, not controllable)
// + setup ~15 + fused ~51 + gaps ~20. This config: CH=8, BLK=256,
// NB=489, publish/spin decoupled lookback, LDS-mirrored cons (vmcnt/
// lgkmcnt decoupling), 32-slot truncated lookback (||M^65536||~3e-9).

#define S_STEPS 999999
#define CH      8
#define BLK     256
#define NB      489          // 489*256*8 = 1,001,472 >= S_STEPS
#define NCHUNK  125000       // active chunks (last partial: 7 steps)
#define LASTFULL 124998      // g <= LASTFULL: To[8g+8] in bounds

// ws float offsets (16B-aligned)
#define OFF_M   0            // 144: M
#define OFF_C   144          // 12
#define OFF_AL  156          // 12
#define OFF_BE  168          // 12
#define OFF_K   192          // 120: K cols [col][12], col0 = const (10 cols)
#define OFF_P2  320          // 8*144: [l]=M^(8*2^l) l=0..5 (M^8..M^256),
                             //        [6]=M^512, [7]=M^1024
#define OFF_PA  1472         // 144: M^1536
#define OFF_PL  1616         // 3*144: M^2048, M^4096, M^6144
#define OFF_PD  2048         // 8*144: Pd[i]=M^(8192*i), i=0..7 (Pd[0]=I)
#define NCONS   3200         // floats mirrored to LDS (= OFF_PD+1152)
#define OFF_AGG 3200         // 489*12 block aggregates (end 9068)
#define OFF_FLAG 9072        // 489 int flags (16B-aligned)

#define FMA4(Q,a,b,c,d,acc) fmaf((Q).w,(d),fmaf((Q).z,(c),fmaf((Q).y,(b),fmaf((Q).x,(a),(acc)))))

// y += P(12x12 row-major, 16B-aligned) * x
__device__ __forceinline__ void mv_acc(const float* Pf, const float* x, float* y) {
  const float4* P = reinterpret_cast<const float4*>(Pf);
#pragma unroll
  for (int i = 0; i < 12; ++i) {
    float4 a = P[3*i], b = P[3*i+1], c = P[3*i+2];
    y[i] = FMA4(c, x[8],x[9],x[10],x[11],
            FMA4(b, x[4],x[5],x[6],x[7],
             FMA4(a, x[0],x[1],x[2],x[3], y[i])));
  }
}

// dot(P row (16B-aligned), xv[0..11] scalars)
__device__ __forceinline__ float rowdot(const float* Prow, const float* xv) {
  const float4* P = reinterpret_cast<const float4*>(Prow);
  float4 a = P[0], b = P[1], c = P[2];
  return FMA4(c, xv[8],xv[9],xv[10],xv[11],
          FMA4(b, xv[4],xv[5],xv[6],xv[7],
           FMA4(a, xv[0],xv[1],xv[2],xv[3], 0.f)));
}

// v = K[:,0] + sum_{s=0..8} K[:,s+1]*tos[s]
__device__ __forceinline__ void fold_chunk(const float* cons,
                                           const float* tos, float* v) {
  const float4* Kq = reinterpret_cast<const float4*>(cons + OFF_K);
  float4 c0=Kq[0], c1=Kq[1], c2=Kq[2];
  v[0]=c0.x; v[1]=c0.y; v[2]=c0.z; v[3]=c0.w;
  v[4]=c1.x; v[5]=c1.y; v[6]=c1.z; v[7]=c1.w;
  v[8]=c2.x; v[9]=c2.y; v[10]=c2.z; v[11]=c2.w;
#pragma unroll
  for (int s = 0; s < 9; ++s) {
    float ts = tos[s];
    float4 ka=Kq[3*(s+1)], kb=Kq[3*(s+1)+1], kc=Kq[3*(s+1)+2];
    v[0]=fmaf(ka.x,ts,v[0]); v[1]=fmaf(ka.y,ts,v[1]); v[2]=fmaf(ka.z,ts,v[2]); v[3]=fmaf(ka.w,ts,v[3]);
    v[4]=fmaf(kb.x,ts,v[4]); v[5]=fmaf(kb.y,ts,v[5]); v[6]=fmaf(kb.z,ts,v[6]); v[7]=fmaf(kb.w,ts,v[7]);
    v[8]=fmaf(kc.x,ts,v[8]); v[9]=fmaf(kc.y,ts,v[9]); v[10]=fmaf(kc.z,ts,v[10]); v[11]=fmaf(kc.w,ts,v[11]);
  }
}

__global__ void __launch_bounds__(512) setup_kernel(
    const float* __restrict__ t_eval, const float* __restrict__ A,
    const float* __restrict__ Bm, const float* __restrict__ loads_raw,
    const float* __restrict__ areas, float* ws) {
  __shared__ double H1[144], H2[144], H3[144], H4[144], Md[144];
  __shared__ double Qa[144], Qb[144];
  __shared__ double C512s[144], C1024s[144], C2048s[144], C4096s[144];
  __shared__ double C8192s[144], C16384s[144], C32768s[144], Pd3s[144];
  __shared__ double cd[12], ald[12], bed[12], b0d[12], bqd[12];
  __shared__ double Vv[3][12], Kd[120];
  int t = threadIdx.x;
  if (t < NB) ((int*)(ws + OFF_FLAG))[t] = 0;   // reset lookback flags
  double h = (double)t_eval[1] - (double)t_eval[0];
  if (t < 144) H1[t] = h * (double)A[t];
  if (t < 12) {
    b0d[t] = (double)Bm[t*11];
    double s = 0.0;
    for (int r = 0; r < 10; ++r) {
      double gq = 50.0 / (1.0 + exp(-(double)loads_raw[10 + r]));
      s += (double)Bm[t*11 + 1 + r] * (gq * (double)areas[r]);
    }
    bqd[t] = s;
  }
  if (t < 120) Kd[t] = 0.0;
  __syncthreads();
  if (t < 144) {                              // H2 = H1*H1
    int i=t/12, j=t%12; double s=0.0;
#pragma unroll
    for (int m = 0; m < 12; ++m) s += H1[i*12+m]*H1[m*12+j];
    H2[t]=s;
  }
  __syncthreads();
  if (t < 288) {                              // H3 = H2*H1 | H4 = H2*H2
    int w=t/144, e=t%144, i=e/12, j=e%12;
    const double* Bp = w ? H2 : H1;
    double s = 0.0;
#pragma unroll
    for (int m = 0; m < 12; ++m) s += H2[i*12+m]*Bp[m*12+j];
    (w ? H4 : H3)[e] = s;
  }
  __syncthreads();
  if (t < 12) {
    double hb=0,h2b=0,h3b=0,hb0=0,h2b0=0,h3b0=0;
#pragma unroll
    for (int m = 0; m < 12; ++m) {
      hb  += H1[t*12+m]*bqd[m]; h2b  += H2[t*12+m]*bqd[m]; h3b  += H3[t*12+m]*bqd[m];
      hb0 += H1[t*12+m]*b0d[m]; h2b0 += H2[t*12+m]*b0d[m]; h3b0 += H3[t*12+m]*b0d[m];
    }
    double h6 = h / 6.0;
    cd[t]  = h6*(6.0*bqd[t] + 3.0*hb + h2b + 0.25*h3b);
    ald[t] = h6*(3.0*b0d[t] + 2.0*hb0 + 0.75*h2b0 + 0.25*h3b0);
    bed[t] = h6*(3.0*b0d[t] + hb0 + 0.25*h2b0);
    Vv[0][t]=ald[t]; Vv[1][t]=bed[t]; Vv[2][t]=cd[t];
    // r=0 K contributions (CH=8): col8 += al, col9 += be, col0 += c
    Kd[96+t] += ald[t]; Kd[108+t] += bed[t]; Kd[t] += cd[t];
  }
  if (t >= 144 && t < 288) {
    int e=t-144, i=e/12, j=e%12;
    Md[e] = (i==j ? 1.0 : 0.0) + H1[e] + 0.5*H2[e] + H3[e]/6.0 + H4[e]/24.0;
  }
  __syncthreads();
  if (t < 144) { ws[OFF_M+t] = (float)Md[t]; Qa[t] = Md[t]; }
  if (t < 12) {
    ws[OFF_C+t]=(float)cd[t]; ws[OFF_AL+t]=(float)ald[t]; ws[OFF_BE+t]=(float)bed[t];
  }
  __syncthreads();
  // chain r=1..15: src=M^(2^(r-1)) -> dst=M^(2^r). Overlapped K rounds
  // r=1..7 (threads 256..291): Vv=M^r*{al,be,c}; Kd cols (8-r),(9-r),0.
  double* src = Qa; double* dst = Qb;
  for (int r = 1; r <= 15; ++r) {
    double acc = 0.0, ks = 0.0;
    if (t < 144) {
      int i=t/12, j=t%12;
#pragma unroll
      for (int m = 0; m < 12; ++m) acc += src[i*12+m]*src[m*12+j];
    }
    int w=0, i2=0;
    if (r <= 7 && t >= 256 && t < 292) {
      w=(t-256)/12; i2=(t-256)%12;
#pragma unroll
      for (int m = 0; m < 12; ++m) ks += Md[i2*12+m]*Vv[w][m];
    }
    __syncthreads();
    if (t < 144) {
      dst[t] = acc;
      if (r >= 3 && r <= 10) ws[OFF_P2+(r-3)*144+t] = (float)acc;  // M^8..M^1024
      if (r == 9)  C512s[t]=acc;
      if (r == 10) C1024s[t]=acc;
      if (r == 11) { C2048s[t]=acc;  ws[OFF_PL+t]       = (float)acc; }
      if (r == 12) { C4096s[t]=acc;  ws[OFF_PL+144+t]   = (float)acc; }
      if (r == 13) { C8192s[t]=acc;  ws[OFF_PD+144+t]   = (float)acc; }  // Pd[1]
      if (r == 14) { C16384s[t]=acc; ws[OFF_PD+2*144+t] = (float)acc; }  // Pd[2]
      if (r == 15) { C32768s[t]=acc; ws[OFF_PD+4*144+t] = (float)acc; }  // Pd[4]
    }
    if (r <= 7 && t >= 256 && t < 292) {
      Vv[w][i2] = ks;
      if (w == 0) Kd[(8-r)*12+i2] += ks;
      else if (w == 1) Kd[(9-r)*12+i2] += ks;
      else Kd[i2] += ks;
    }
    __syncthreads();
    double* tmp = src; src = dst; dst = tmp;    // src = M^(2^r)
  }
  if (t < 120) ws[OFF_K+t] = (float)Kd[t];
  if (t < 144) ws[OFF_PD+t] = (t % 13 == 0) ? 1.f : 0.f;   // Pd[0]=I
  // product round A: M^1536=C512*C1024 ; M^6144=C2048*C4096 ;
  //                  Pd3=C8192*C16384
  if (t < 432) {
    int w=t/144, e=t%144, i=e/12, j=e%12;
    const double* Ap = (w==0) ? C512s  : ((w==1) ? C2048s : C8192s);
    const double* Bp = (w==0) ? C1024s : ((w==1) ? C4096s : C16384s);
    double s = 0.0;
#pragma unroll
    for (int m = 0; m < 12; ++m) s += Ap[i*12+m]*Bp[m*12+j];
    if (w==0) ws[OFF_PA+e] = (float)s;
    else if (w==1) ws[OFF_PL+2*144+e] = (float)s;
    else { ws[OFF_PD+3*144+e] = (float)s; Pd3s[e] = s; }
  }
  __syncthreads();
  // product round B: Pd5=Pd1*Pd4 ; Pd6=Pd2*Pd4 ; Pd7=Pd3*Pd4
  if (t < 432) {
    int w=t/144, e=t%144, i=e/12, j=e%12;
    const double* Ap = (w==0) ? C8192s : ((w==1) ? C16384s : Pd3s);
    double s = 0.0;
#pragma unroll
    for (int m = 0; m < 12; ++m) s += Ap[i*12+m]*C32768s[m*12+j];
    ws[OFF_PD+(5+w)*144+e] = (float)s;
  }
}

// Fused: LDS-mirror cons; fold+scan ONCE; publish agg[b] (release flag);
// spin on 32 predecessor flags (acquire); truncated lookback + merged
// prefix + 8-step expand. Plain launch, graph-capturable.
__global__ void __launch_bounds__(BLK, 2) fused_scan(
    const float* __restrict__ cons, const float* __restrict__ To,
    const float* __restrict__ x0, float* __restrict__ agg,
    int* __restrict__ flags, float* __restrict__ out) {
  __shared__ __align__(16) float Lc[NCONS];   // LDS mirror of cons[0..3200)
  __shared__ __align__(16) float Tw[48];      // wave totals
  __shared__ __align__(16) float Ta[24];      // agg tree level 1
  __shared__ __align__(16) float Pw[48];      // wave exclusive prefixes
  __shared__ __align__(16) float lkb[32*12];  // lookback stage-1 partials
  __shared__ __align__(16) float yv[8*12];
  __shared__ __align__(16) float zv[8*12];
  __shared__ __align__(16) float Xs[12];
  __shared__ __align__(16) float Qw[48];      // M^(512w)*Xs + Pw
  int k = threadIdx.x, b = blockIdx.x;
  int g = b*BLK + k, base = g*CH;
  bool active = (g < NCHUNK), fullc = (g <= LASTFULL);
  float to_[9];
#pragma unroll
  for (int i = 0; i < 9; ++i) to_[i] = 0.f;
  if (active) {
    const float4* tp = reinterpret_cast<const float4*>(To + base);
    float4 ta = tp[0], tb = tp[1];
    to_[0]=ta.x; to_[1]=ta.y; to_[2]=ta.z; to_[3]=ta.w;
    to_[4]=tb.x; to_[5]=tb.y; to_[6]=tb.z; to_[7]=tb.w;
    to_[8] = fullc ? To[base+8] : 0.f;
  }
  {                                  // mirror cons -> LDS (800 float4)
    const float4* s4 = reinterpret_cast<const float4*>(cons);
    float4* d4 = reinterpret_cast<float4*>(Lc);
#pragma unroll
    for (int r = 0; r < 4; ++r) {
      int idx = k + r*BLK;
      if (idx < NCONS/4) d4[idx] = s4[idx];
    }
  }
  __syncthreads();
  const float* lc = Lc;              // all constant reads now LDS
  float v[12];
  if (fullc) fold_chunk(lc, to_, v);
  else {
#pragma unroll
    for (int i = 0; i < 12; ++i) v[i] = 0.f;
  }
  if (g == 0) {                      // fold x0 into chunk 0: v += M^8 x0
    float xi[12];
#pragma unroll
    for (int i = 0; i < 12; ++i) xi[i] = x0[i];
    mv_acc(lc + OFF_P2, xi, v);
  }
  int j = k & 63, w = k >> 6;
#pragma unroll
  for (int l = 0; l < 6; ++l) {      // in-wave inclusive scan
    int off = 1 << l;
    float nb[12];
#pragma unroll
    for (int i = 0; i < 12; ++i) nb[i] = __shfl_up(v[i], (unsigned)off, 64);
    if (j >= off) mv_acc(lc + OFF_P2 + l*144, nb, v);
  }
  float se[12];                      // exclusive in-wave scan
#pragma unroll
  for (int i = 0; i < 12; ++i) {
    float u = __shfl_up(v[i], 1u, 64);
    se[i] = (j == 0) ? 0.f : u;
  }
  if (j == 63) {
#pragma unroll
    for (int i = 0; i < 12; ++i) Tw[w*12 + i] = v[i];
  }
  __syncthreads();
  if (k < 24) {                      // (T0,T1),(T2,T3): M^512*left + right
    int p = k/12, comp = k - p*12;
    Ta[k] = rowdot(lc + OFF_P2 + 6*144 + comp*12, Tw + 2*p*12)
          + Tw[(2*p+1)*12 + comp];
  }
  __syncthreads();
  if (k < 12) {                      // agg[b] = M^1024*Ta0 + Ta1 (agent)
    float val = rowdot(lc + OFF_P2 + 7*144 + k*12, Ta) + Ta[12 + k];
    __hip_atomic_store(&agg[b*12 + k], val, __ATOMIC_RELAXED,
                       __HIP_MEMORY_SCOPE_AGENT);
  }
  __syncthreads();
  if (k == 0)                        // publish: release flag
    __hip_atomic_store(&flags[b], 1, __ATOMIC_RELEASE,
                       __HIP_MEMORY_SCOPE_AGENT);
  // spin on 32 predecessors (threads k<32, one flag each)
  if (k < 32) {
    int src = b - 1 - k;
    if (src >= 0) {
      while (__hip_atomic_load(&flags[src], __ATOMIC_ACQUIRE,
                               __HIP_MEMORY_SCOPE_AGENT) == 0) {
        __builtin_amdgcn_s_sleep(1);
      }
    }
  }
  __syncthreads();
  // lookback stage 1: slot=4i+jj: lkb[slot] = M^(2048*jj)*agg[b-1-slot]
#pragma unroll
  for (int r = 0; r < 2; ++r) {
    int idx = k + r*BLK;             // covers 384 = 32*12
    if (idx < 384) {
      int slot = idx / 12, comp = idx - slot*12;
      int src = b - 1 - slot;
      float acc = 0.f;
      if (src >= 0) {
        int jj = slot & 3;
        const float* ag = agg + src*12;
        acc = (jj == 0) ? ag[comp]
            : rowdot(lc + OFF_PL + (jj-1)*144 + comp*12, ag);
      }
      lkb[idx] = acc;
    }
  }
  __syncthreads();
  // yv[i] = sum_jj lkb[4i+jj]  (k<96)  |  Pw: P0=0, P1=T0  (k in [192,216))
  if (k < 96) {
    int i = k/12, comp = k - i*12;
    yv[k] = lkb[(4*i)*12+comp] + lkb[(4*i+1)*12+comp]
          + lkb[(4*i+2)*12+comp] + lkb[(4*i+3)*12+comp];
  } else if (k >= 192 && k < 216) {
    int q = k - 192;                 // 0..23
    if (q < 12) Pw[q] = 0.f;         // P0
    else Pw[q] = Tw[q-12];           // P1 = T0
  }
  __syncthreads();
  // zv[i] = M^(8192i)*yv[i] (k<96) | P2 = M^512*P1 + T1 (k in [192,204))
  if (k < 96) {
    int i = k/12, comp = k - i*12;
    zv[k] = (i == 0) ? yv[comp]
          : rowdot(lc + OFF_PD + i*144 + comp*12, yv + i*12);
  } else if (k >= 192 && k < 204) {
    int comp = k - 192;
    Pw[24+comp] = rowdot(lc + OFF_P2 + 6*144 + comp*12, Pw+12) + Tw[12+comp];
  }
  __syncthreads();
  // Xs = sum_i zv[i] (k<12) | P3 = M^512*P2 + T2 (k in [192,204))
  if (k < 12) {
    float s = 0.f;
#pragma unroll
    for (int i = 0; i < 8; ++i) s += zv[i*12 + k];
    Xs[k] = s;
  } else if (k >= 192 && k < 204) {
    int comp = k - 192;
    Pw[36+comp] = rowdot(lc + OFF_P2 + 6*144 + comp*12, Pw+24) + Tw[24+comp];
  }
  __syncthreads();
  // Qw[w] = M^(512w)*Xs + Pw[w]  (w=0..3; matrices I, M^512, M^1024, M^1536)
  if (k < 48) {
    int ww = k/12, comp = k - ww*12;
    float acc;
    if (ww == 0) acc = Xs[comp];
    else if (ww == 1) acc = rowdot(lc + OFF_P2 + 6*144 + comp*12, Xs);
    else if (ww == 2) acc = rowdot(lc + OFF_P2 + 7*144 + comp*12, Xs);
    else acc = rowdot(lc + OFF_PA + comp*12, Xs);
    Qw[k] = acc + Pw[k];
  }
  __syncthreads();
  if (!active) return;               // all barriers done
  // per-thread: x = M^(8j)*Qw[w] + se   (bits of j, P2[0..5])
  float x[12];
#pragma unroll
  for (int i = 0; i < 12; ++i) x[i] = Qw[w*12 + i];
#pragma unroll
  for (int l = 0; l < 6; ++l) {
    if ((j >> l) & 1) {
      float vn[12];
#pragma unroll
      for (int i = 0; i < 12; ++i) vn[i] = 0.f;
      mv_acc(lc + OFF_P2 + l*144, x, vn);
#pragma unroll
      for (int i = 0; i < 12; ++i) x[i] = vn[i];
    }
  }
#pragma unroll
  for (int i = 0; i < 12; ++i) x[i] += se[i];
  if (b == 0 && k == 0) {
#pragma unroll
    for (int i = 0; i < 12; ++i) x[i] += x0[i];      // start state = x0
#pragma unroll
    for (int i = 0; i < 12; ++i) out[i] = x0[i];     // row 0
  }
  // expand: 8 unconditional steps, predicated stores (NO break).
  // M, c, al, be read from LDS (lgkmcnt) -- decoupled from store vmcnt.
  float cv[12], av[12], bv[12];
#pragma unroll
  for (int i = 0; i < 12; ++i) {
    cv[i] = lc[OFF_C + i]; av[i] = lc[OFF_AL + i]; bv[i] = lc[OFF_BE + i];
  }
  const float4* Mq = reinterpret_cast<const float4*>(lc + OFF_M);
#pragma unroll
  for (int s = 0; s < CH; ++s) {
    float tot = to_[s], ton = to_[s+1];
    float xn[12];
#pragma unroll
    for (int i = 0; i < 12; ++i) {
      float4 a = Mq[3*i], bq = Mq[3*i+1], c = Mq[3*i+2];
      xn[i] = FMA4(c, x[8],x[9],x[10],x[11],
               FMA4(bq, x[4],x[5],x[6],x[7],
                FMA4(a, x[0],x[1],x[2],x[3],
                 fmaf(bv[i],ton,fmaf(av[i],tot,cv[i])))));
    }
    int tt = base + s;
    if (tt < S_STEPS) {
      float4* op = reinterpret_cast<float4*>(out + (size_t)(tt+1)*12);
      op[0] = make_float4(xn[0],xn[1],xn[2],xn[3]);
      op[1] = make_float4(xn[4],xn[5],xn[6],xn[7]);
      op[2] = make_float4(xn[8],xn[9],xn[10],xn[11]);
    }
#pragma unroll
    for (int i = 0; i < 12; ++i) x[i] = xn[i];
  }
}

extern "C" void kernel_launch(void* const* d_in, const int* in_sizes, int n_in,
                              void* d_out, int out_size, void* d_ws, size_t ws_size,
                              hipStream_t stream) {
  const float* t_eval    = (const float*)d_in[0];
  const float* x0        = (const float*)d_in[1];
  const float* A         = (const float*)d_in[2];
  const float* B         = (const float*)d_in[3];
  const float* To        = (const float*)d_in[4];
  const float* loads_raw = (const float*)d_in[5];
  const float* areas     = (const float*)d_in[6];
  float* out = (float*)d_out;
  float* ws  = (float*)d_ws;

  setup_kernel<<<1, 512, 0, stream>>>(t_eval, A, B, loads_raw, areas, ws);
  fused_scan<<<NB, BLK, 0, stream>>>(ws, To, x0, ws + OFF_AGG,
                                     (int*)(ws + OFF_FLAG), out);
}